// Round 9
// baseline (341.468 us; speedup 1.0000x reference)
//
#include <hip/hip_runtime.h>

// Problem constants (B,T,D,H from reference)
#define B_  4
#define T_  2048
#define D_  1024
#define H_  16
#define HD_ 64
#define BT_ (B_*T_)   // 8192
#define K_  D_        // 1024 (GEMM inner dim)

typedef unsigned short u16;
typedef unsigned int   u32;

typedef __attribute__((ext_vector_type(8))) short bf16x8;  // 8 bf16 (4 VGPRs)
typedef __attribute__((ext_vector_type(4))) float f32x4;   // MFMA 16x16 C/D

__device__ __forceinline__ u16 f2bf(float f) {
  u32 u = __builtin_bit_cast(u32, f);
  u += 0x7fffu + ((u >> 16) & 1u);   // round-to-nearest-even
  return (u16)(u >> 16);
}

// packed f32x2 -> bf16x2 (RNE), single VALU op; D[15:0]=lo, D[31:16]=hi
__device__ __forceinline__ u32 cvtpk(float lo, float hi) {
  u32 r;
  __asm__("v_cvt_pk_bf16_f32 %0, %1, %2" : "=v"(r) : "v"(lo), "v"(hi));
  return r;
}

#define GLOAD_LDS16(g, l) __builtin_amdgcn_global_load_lds(                  \
    (const __attribute__((address_space(1))) void*)(g),                      \
    (__attribute__((address_space(3))) void*)(l), 16, 0, 0)

// compiler-only memory barrier: forbids IR reordering of LDS/global ops
#define MEMBAR() __asm__ volatile("" ::: "memory")
#define SCHEDB() __builtin_amdgcn_sched_barrier(0)
#define SBAR()   __builtin_amdgcn_s_barrier()

#define SFC 0.18033688011f   /* 0.125 * log2(e); folded into Q projection */

// ---------------- fp32 -> bf16 weight converts (4 matrices, 1 dispatch) -------
__global__ __launch_bounds__(256) void cvt4_f32_bf16(
    const float* __restrict__ i0, const float* __restrict__ i1,
    const float* __restrict__ i2, const float* __restrict__ i3,
    u16* __restrict__ o0, u16* __restrict__ o1,
    u16* __restrict__ o2, u16* __restrict__ o3, int cvw) {
  const int blk = blockIdx.x;
  const int seg = blk / cvw;           // 0..3
  const int ib  = blk - seg*cvw;
  const float* in = seg==0 ? i0 : (seg==1 ? i1 : (seg==2 ? i2 : i3));
  u16* out        = seg==0 ? o0 : (seg==1 ? o1 : (seg==2 ? o2 : o3));
  const int i = ib*256 + threadIdx.x;
  float4 x = ((const float4*)in)[i];
  ((uint2*)out)[i] = make_uint2(cvtpk(x.x, x.y), cvtpk(x.z, x.w));
}

// ---------------- GEMM: 128x128, BK=32, fp32-A convert-in-kernel --------------
// A is the RAW FP32 activation (q/k/v) — the former cvt3 pass is absorbed:
// per K-step, A(t+1) is written to LDS from regs LOADED LAST ITERATION
// (aged a full iteration -> the compiler's vmcnt for them is free), THEN the
// same reg set is reloaded with A(t+2) (WAR reuse, single 16-VGPR set).
// This is the round-6 fold with the ordering fixed: WRITEA before MFMA, reg
// age = 1 full iteration, and the end-of-step wait stays counted: B's
// global_load_lds issue FIRST, reg-loads second, so `s_waitcnt vmcnt(4)`
// drains exactly B(t+1) and leaves the 4 reg-loads in flight.
// A global map: 8 thr/row (128B contiguous per row, coalesced fp32).
// A LDS layout identical to round 8 (bf16, slot c at phys c^((row>>1)&3)),
// so the frag-read side is byte-for-byte unchanged.
// QKV-fused: seg = blockIdx.x>>9; seg==2 writes V transposed to Vt[b,h,hd,t].
__global__ __launch_bounds__(256, 4) void gemm_qkv(
    const float* __restrict__ A0, const float* __restrict__ A1,
    const float* __restrict__ A2,
    const u16* __restrict__ W0, const u16* __restrict__ W1,
    const u16* __restrict__ W2,
    const float* __restrict__ b0, const float* __restrict__ b1,
    const float* __restrict__ b2,
    u16* __restrict__ O0, u16* __restrict__ O1, u16* __restrict__ O2,
    float osc0)
{
  __shared__ u16 As[2][128 * 32];   // [buf][row][slot][8]  (bf16)
  __shared__ u16 Bs[2][128 * 32];

  const int tid  = threadIdx.x;
  const int wave = tid >> 6;
  const int lane = tid & 63;
  const int col  = lane & 15;
  const int quad = lane >> 4;
  const int wy   = wave >> 1;          // m-half (64)
  const int wx   = wave & 1;           // n-half (64)

  const int seg   = blockIdx.x >> 9;   // 0=Q 1=K 2=V
  const int inner = blockIdx.x & 511;
  const float* A   = seg==0 ? A0 : (seg==1 ? A1 : A2);
  const u16*   W   = seg==0 ? W0 : (seg==1 ? W1 : W2);
  const float* bias = seg==0 ? b0 : (seg==1 ? b1 : b2);
  u16*         Out = seg==0 ? O0 : (seg==1 ? O1 : O2);
  const float oscale = (seg == 0) ? osc0 : 1.0f;

  // XCD-clustered swizzle within the 512-block segment
  const int xcd = inner & 7;
  const int jj  = inner >> 3;          // 0..63
  const int m0 = (xcd*8 + (jj & 7)) * 128;
  const int n0 = (jj >> 3) * 128;

  // B staging (unchanged): 4 thr/row, slot tid&3 holds k-chunk (tid&3)^((row>>1)&3)
  const int srow = tid >> 2;                           // 0..63
  const int kseg = ((tid & 3) ^ ((srow >> 1) & 3)) * 8;
  const u16* bgp = W + (size_t)(n0 + srow) * K_ + kseg;

  // A reg-staging: 8 thr/row (float offset (tid&7)*4), 4 row-groups of 32.
  // LDS dest (u16): row(tid>>3)*32 + (chunk^xsel)*8 + half*4, group adds 1024.
  //   chunk = (tid>>1)&3, half = tid&1, xsel = (row>>1)&3 = (tid>>4)&3
  //   (group rows g*32 keep (row>>1)&3 invariant: g*16 ≡ 0 mod 4)
  const float* agp = A + (size_t)(m0 + (tid >> 3)) * K_ + (tid & 7) * 4;
  const int awo = (tid >> 3) * 32
                + ((((tid >> 1) & 3) ^ ((tid >> 4) & 3)) * 8)
                + (tid & 1) * 4;

  float4 r0, r1, r2, r3;               // in-flight fp32 A (single set, WAR-reused)

#define LOADA(kn) {                                                          \
    r0 = *(const float4*)(agp + (kn));                                       \
    r1 = *(const float4*)(agp + (size_t)32*K_ + (kn));                       \
    r2 = *(const float4*)(agp + (size_t)64*K_ + (kn));                       \
    r3 = *(const float4*)(agp + (size_t)96*K_ + (kn)); }
#define ISSB(buf, kn) {                                                      \
    GLOAD_LDS16(bgp + (kn),                 &Bs[buf][tid*8]);                \
    GLOAD_LDS16(bgp + (size_t)64*K_ + (kn), &Bs[buf][2048 + tid*8]); }
#define WRITEA(buf) {                                                        \
    *(uint2*)(&As[buf][awo])        = make_uint2(cvtpk(r0.x,r0.y), cvtpk(r0.z,r0.w)); \
    *(uint2*)(&As[buf][awo + 1024]) = make_uint2(cvtpk(r1.x,r1.y), cvtpk(r1.z,r1.w)); \
    *(uint2*)(&As[buf][awo + 2048]) = make_uint2(cvtpk(r2.x,r2.y), cvtpk(r2.z,r2.w)); \
    *(uint2*)(&As[buf][awo + 3072]) = make_uint2(cvtpk(r3.x,r3.y), cvtpk(r3.z,r3.w)); }

  f32x4 acc[4][4];
  const f32x4 z = {0.f, 0.f, 0.f, 0.f};
#pragma unroll
  for (int i = 0; i < 4; ++i)
#pragma unroll
    for (int j = 0; j < 4; ++j) acc[i][j] = z;

  // frag LDS offsets (u16): row*32 + (quad ^ ((row>>1)&3))*8  (unchanged)
  u32 aro[4], bro[4];
#pragma unroll
  for (int i = 0; i < 4; ++i) {
    const int ar = wy*64 + i*16 + col;
    const int br = wx*64 + i*16 + col;
    aro[i] = (u32)(ar*32 + ((quad ^ ((ar >> 1) & 3)) * 8));
    bro[i] = (u32)(br*32 + ((quad ^ ((br >> 1) & 3)) * 8));
  }

  // fragment-read + MFMA block (reads buf c_)
#define FRAG_MFMA(c_) {                                                      \
    bf16x8 af[4], bfr[4];                                                    \
    _Pragma("unroll")                                                        \
    for (int i = 0; i < 4; ++i) af[i]  = *(const bf16x8*)(&As[c_][aro[i]]);  \
    _Pragma("unroll")                                                        \
    for (int i = 0; i < 4; ++i) bfr[i] = *(const bf16x8*)(&Bs[c_][bro[i]]);  \
    __asm__ volatile("s_waitcnt lgkmcnt(0)" ::: "memory");                   \
    SCHEDB();                                                                \
    __builtin_amdgcn_s_setprio(1);                                           \
    _Pragma("unroll")                                                        \
    for (int mt = 0; mt < 4; ++mt)                                           \
      _Pragma("unroll")                                                      \
      for (int nt = 0; nt < 4; ++nt)                                         \
        acc[mt][nt] = __builtin_amdgcn_mfma_f32_16x16x32_bf16(               \
            bfr[nt], af[mt], acc[mt][nt], 0, 0, 0);                          \
    __builtin_amdgcn_s_setprio(0);                                           \
    SCHEDB(); }

  // prologue: tile0 -> buf0; leave A(1) reg-loads in flight
  LOADA(0);
  WRITEA(0);                       // compiler drains the 4 reg-loads (one-time)
  ISSB(0, 0);                      // B(0): 2 gload_lds
  LOADA(32);                       // A(1) regs (issued AFTER B -> vmcnt order)
  MEMBAR();
  __asm__ volatile("s_waitcnt vmcnt(4)" ::: "memory");   // B(0) landed
  __asm__ volatile("s_waitcnt lgkmcnt(0)" ::: "memory"); // A(0) writes done
  SCHEDB();
  SBAR();
  MEMBAR();

  // main loop: t = 0..29 full pipeline
  for (int t = 0; t < 30; ++t) {
    const int cur = t & 1;
    ISSB(cur ^ 1, (t + 1) * 32);   // B(t+1) (oldest outstanding after this iter)
    MEMBAR();
    WRITEA(cur ^ 1);               // A(t+1) from regs aged 1 iter (free wait)
    LOADA((t + 2) * 32);           // A(t+2) into same regs (WAR)
    MEMBAR();
    FRAG_MFMA(cur);
    __asm__ volatile("s_waitcnt vmcnt(4)" ::: "memory");  // drains B(t+1) only
    SCHEDB();
    SBAR();
    MEMBAR();
  }
  // t = 30: stage tile 31, no further reg-loads
  {
    ISSB(1, 31 * 32);
    MEMBAR();
    WRITEA(1);                     // A(31)
    MEMBAR();
    FRAG_MFMA(0);
    __asm__ volatile("s_waitcnt vmcnt(0)" ::: "memory");
    SCHEDB();
    SBAR();
    MEMBAR();
  }
  // t = 31: compute only
  FRAG_MFMA(1);
#undef LOADA
#undef ISSB
#undef WRITEA
#undef FRAG_MFMA

  // epilogue: lane holds 4 consecutive n per (mt,nt)
#pragma unroll
  for (int nt = 0; nt < 4; ++nt) {
    const int nb = n0 + wx*64 + nt*16 + quad*4;
    const float4 bv = *(const float4*)&bias[nb];
#pragma unroll
    for (int mt = 0; mt < 4; ++mt) {
      const int m = m0 + wy*64 + mt*16 + col;
      const float v0 = (acc[mt][nt][0] + bv.x) * oscale;
      const float v1 = (acc[mt][nt][1] + bv.y) * oscale;
      const float v2 = (acc[mt][nt][2] + bv.z) * oscale;
      const float v3 = (acc[mt][nt][3] + bv.w) * oscale;
      if (seg != 2) {
        uint2 w2 = make_uint2(cvtpk(v0, v1), cvtpk(v2, v3));
        *(uint2*)&Out[(size_t)m * D_ + nb] = w2;
      } else {
        // V: write transposed Vt[(b*16+h)*64+hd][t]
        const int bb = m >> 11, tt = m & 2047;
        const int h = nb >> 6, hd = nb & 63;
        u16* vp = Out + ((size_t)((bb*16 + h)*64 + hd)) * 2048 + tt;
        vp[0]    = f2bf(v0);
        vp[2048] = f2bf(v1);
        vp[4096] = f2bf(v2);
        vp[6144] = f2bf(v3);
      }
    }
  }
}

// ---------------- O-projection GEMM: 64x128 tile, grid 1024 -------------------
// (round-4 proven structure: 4 blocks/CU, counted vmcnt(3), bias epilogue)
__global__ __launch_bounds__(256, 4) void gemm_o(
    const u16* __restrict__ A, const u16* __restrict__ W,
    const float* __restrict__ bias, float* __restrict__ Out)
{
  __shared__ u16 As[2][64 * 32];
  __shared__ u16 Bs[2][128 * 32];

  const int tid  = threadIdx.x;
  const int wave = tid >> 6;
  const int lane = tid & 63;
  const int col  = lane & 15;
  const int quad = lane >> 4;
  const int wy   = wave >> 1;          // m-half (32)
  const int wx   = wave & 1;           // n-half (64)

  const int xcd = blockIdx.x & 7;
  const int jj  = blockIdx.x >> 3;     // 0..127
  const int m0 = (xcd*16 + (jj & 15)) * 64;
  const int n0 = (jj >> 4) * 128;

  const int srow = tid >> 2;                           // 0..63
  const int kseg = ((tid & 3) ^ ((srow >> 1) & 3)) * 8;
  const u16* agp = A + (size_t)(m0 + srow) * K_ + kseg;
  const u16* bgp = W + (size_t)(n0 + srow) * K_ + kseg;

  f32x4 acc[2][4];
  const f32x4 z = {0.f, 0.f, 0.f, 0.f};
#pragma unroll
  for (int i = 0; i < 2; ++i)
#pragma unroll
    for (int j = 0; j < 4; ++j) acc[i][j] = z;

  u32 aro[2], bro[4];
#pragma unroll
  for (int i = 0; i < 2; ++i) {
    const int ar = wy*32 + i*16 + col;
    aro[i] = (u32)(ar*32 + ((quad ^ ((ar >> 1) & 3)) * 8));
  }
#pragma unroll
  for (int i = 0; i < 4; ++i) {
    const int br = wx*64 + i*16 + col;
    bro[i] = (u32)(br*32 + ((quad ^ ((br >> 1) & 3)) * 8));
  }

  auto STAGE = [&](int buf, int k0) {
    GLOAD_LDS16(agp + k0,                 &As[buf][tid*8]);
    GLOAD_LDS16(bgp + k0,                 &Bs[buf][tid*8]);
    GLOAD_LDS16(bgp + (size_t)64*K_ + k0, &Bs[buf][2048 + tid*8]);
  };

  STAGE(0, 0);
  MEMBAR();

  int cur = 0;
  for (int k0 = 0; k0 < K_; k0 += 32) {
    if (k0 + 32 < K_) {
      STAGE(cur ^ 1, k0 + 32);    // prefetch next K-slice (3 loads/wave)
      MEMBAR();
      __asm__ volatile("s_waitcnt vmcnt(3)" ::: "memory");
    } else {
      __asm__ volatile("s_waitcnt vmcnt(0)" ::: "memory");
    }
    SCHEDB();
    SBAR();
    MEMBAR();
    SCHEDB();

    bf16x8 af[2], bfr[4];
#pragma unroll
    for (int i = 0; i < 2; ++i) af[i]  = *(const bf16x8*)(&As[cur][aro[i]]);
#pragma unroll
    for (int i = 0; i < 4; ++i) bfr[i] = *(const bf16x8*)(&Bs[cur][bro[i]]);
    __asm__ volatile("s_waitcnt lgkmcnt(0)" ::: "memory");
    SCHEDB();
#pragma unroll
    for (int mt = 0; mt < 2; ++mt)
#pragma unroll
      for (int nt = 0; nt < 4; ++nt)
        acc[mt][nt] = __builtin_amdgcn_mfma_f32_16x16x32_bf16(
            bfr[nt], af[mt], acc[mt][nt], 0, 0, 0);

    SCHEDB();
    SBAR();
    MEMBAR();
    SCHEDB();
    cur ^= 1;
  }

#pragma unroll
  for (int nt = 0; nt < 4; ++nt) {
    const int nb = n0 + wx*64 + nt*16 + quad*4;
    const float4 bv = *(const float4*)&bias[nb];
#pragma unroll
    for (int mt = 0; mt < 2; ++mt) {
      const int m = m0 + wy*32 + mt*16 + col;
      float4 f4 = {acc[mt][nt][0] + bv.x, acc[mt][nt][1] + bv.y,
                   acc[mt][nt][2] + bv.z, acc[mt][nt][3] + bv.w};
      *(float4*)&Out[(size_t)m * D_ + nb] = f4;
    }
  }
}

// ---------------- Flash attention: dbuf-staged K/V, 128-row q-blocks ----------
// (cvtpk version — verified; frozen)
__global__ __launch_bounds__(256) void attn_fwd(
    const u16* __restrict__ Qp, const u16* __restrict__ Kp,
    const u16* __restrict__ Vt, u16* __restrict__ Oout)
{
  __shared__ u16 Ks[2 * 4096];  // [buf][slot=hd/8][row=j][8]
  __shared__ u16 Vs[2 * 4096];  // [buf][slot=t/8][row=hd][8]
  __shared__ __align__(16) u16 plds[4 * 32 * 72];   // per-wave P, stride 72

  const int tid  = threadIdx.x;
  const int wave = tid >> 6;
  const int lane = tid & 63;
  const int col  = lane & 15;
  const int quad = lane >> 4;
  const int blk  = blockIdx.x;
  const int bh   = blk & 63;
  const int qt   = 15 - (blk >> 6);   // longest blocks first
  const int b = bh >> 4, h = bh & 15;
  const int rb0 = qt*128 + wave*16;   // group0 rows
  const int q0 = rb0 + col;
  const int q1 = q0 + 64;

  u16* const pl = plds + wave * 32 * 72;   // rows 0..15 grp0, 16..31 grp1

  bf16x8 qa0, qa1, qb0, qb1;
  {
    const u16* qr = Qp + (size_t)(b*T_ + q0) * D_ + h*HD_ + quad*8;
    qa0 = *(const bf16x8*)(qr);
    qa1 = *(const bf16x8*)(qr + 32);
    qr += (size_t)64 * D_;
    qb0 = *(const bf16x8*)(qr);
    qb1 = *(const bf16x8*)(qr + 32);
  }

  const u16* kbase = Kp + (size_t)(b*T_) * D_ + h*HD_;
  const u16* vbase = Vt + (size_t)(bh*HD_) * T_;

  const int srow  = tid & 63;
  const int sslot = tid >> 6;
  const u16* kg0 = kbase + (size_t)srow * D_ + sslot*8;
  const u16* kg1 = kbase + (size_t)srow * D_ + (4+sslot)*8;
  const u16* vg0 = vbase + (size_t)srow * T_ + sslot*8;
  const u16* vg1 = vbase + (size_t)srow * T_ + (4+sslot)*8;

  const f32x4 z = {0.f, 0.f, 0.f, 0.f};
  f32x4 oa[4], ob[4];
#pragma unroll
  for (int dt = 0; dt < 4; ++dt) { oa[dt] = z; ob[dt] = z; }
  f32x4 la = z, lb = z;

  const int jend0  = qt * 128;
  const int jend1  = qt * 128 + 64;
  const int ntiles = (jend1 >> 6) + 1;

  GLOAD_LDS16(kg0, Ks + tid*8);
  GLOAD_LDS16(kg1, Ks + 2048 + tid*8);
  GLOAD_LDS16(vg0, Vs + tid*8);
  GLOAD_LDS16(vg1, Vs + 2048 + tid*8);
  __syncthreads();

  int cur = 0;
  for (int t = 0; t < ntiles; ++t) {
    const int j0 = t << 6;

    if (t + 1 < ntiles) {
      const int jn = j0 + 64;
      const size_t kj = (size_t)jn * D_;
      u16* kb = Ks + (cur ^ 1) * 4096;
      u16* vb = Vs + (cur ^ 1) * 4096;
      GLOAD_LDS16(kg0 + kj, kb + tid*8);
      GLOAD_LDS16(kg1 + kj, kb + 2048 + tid*8);
      GLOAD_LDS16(vg0 + jn, vb + tid*8);
      GLOAD_LDS16(vg1 + jn, vb + 2048 + tid*8);
    }
    MEMBAR();

    const u16* kr = Ks + cur * 4096;
    const u16* vr = Vs + cur * 4096;

    f32x4 sa[4], sb[4];
    __builtin_amdgcn_s_setprio(1);
#pragma unroll
    for (int jt = 0; jt < 4; ++jt) {
      bf16x8 kf0 = *(const bf16x8*)(kr + (quad*64 + jt*16 + col) * 8);
      bf16x8 kf1 = *(const bf16x8*)(kr + 2048 + (quad*64 + jt*16 + col) * 8);
      sa[jt] = __builtin_amdgcn_mfma_f32_16x16x32_bf16(kf0, qa0, z, 0,0,0);
      sa[jt] = __builtin_amdgcn_mfma_f32_16x16x32_bf16(kf1, qa1, sa[jt], 0,0,0);
      sb[jt] = __builtin_amdgcn_mfma_f32_16x16x32_bf16(kf0, qb0, z, 0,0,0);
      sb[jt] = __builtin_amdgcn_mfma_f32_16x16x32_bf16(kf1, qb1, sb[jt], 0,0,0);
    }
    __builtin_amdgcn_s_setprio(0);

    if (j0 >= jend0) {
      const int dq = q0 - j0;
#pragma unroll
      for (int jt = 0; jt < 4; ++jt)
#pragma unroll
        for (int r = 0; r < 4; ++r) {
          const int jo = jt*16 + quad*4 + r;
          sa[jt][r] = (jo > dq) ? 0.f : __builtin_amdgcn_exp2f(sa[jt][r]);
        }
    } else {
#pragma unroll
      for (int jt = 0; jt < 4; ++jt)
#pragma unroll
        for (int r = 0; r < 4; ++r)
          sa[jt][r] = __builtin_amdgcn_exp2f(sa[jt][r]);
    }
    if (j0 >= jend1) {
      const int dq = q1 - j0;
#pragma unroll
      for (int jt = 0; jt < 4; ++jt)
#pragma unroll
        for (int r = 0; r < 4; ++r) {
          const int jo = jt*16 + quad*4 + r;
          sb[jt][r] = (jo > dq) ? 0.f : __builtin_amdgcn_exp2f(sb[jt][r]);
        }
    } else {
#pragma unroll
      for (int jt = 0; jt < 4; ++jt)
#pragma unroll
        for (int r = 0; r < 4; ++r)
          sb[jt][r] = __builtin_amdgcn_exp2f(sb[jt][r]);
    }
#pragma unroll
    for (int jt = 0; jt < 4; ++jt) { la += sa[jt]; lb += sb[jt]; }

    {
      u16* prow = pl + col * 72;
#pragma unroll
      for (int jt = 0; jt < 4; ++jt) {
        uint2 w2;
        w2.x = cvtpk(sa[jt][0], sa[jt][1]);
        w2.y = cvtpk(sa[jt][2], sa[jt][3]);
        *(uint2*)(prow + jt*16 + quad*4) = w2;
      }
      prow = pl + (16 + col) * 72;
#pragma unroll
      for (int jt = 0; jt < 4; ++jt) {
        uint2 w2;
        w2.x = cvtpk(sb[jt][0], sb[jt][1]);
        w2.y = cvtpk(sb[jt][2], sb[jt][3]);
        *(uint2*)(prow + jt*16 + quad*4) = w2;
      }
    }
    MEMBAR();

    {
      bf16x8 pa0 = *(const bf16x8*)(pl + col*72 + quad*8);
      bf16x8 pa1 = *(const bf16x8*)(pl + col*72 + 32 + quad*8);
      bf16x8 pb0 = *(const bf16x8*)(pl + (16+col)*72 + quad*8);
      bf16x8 pb1 = *(const bf16x8*)(pl + (16+col)*72 + 32 + quad*8);
      __builtin_amdgcn_s_setprio(1);
#pragma unroll
      for (int dt = 0; dt < 4; ++dt) {
        bf16x8 v0 = *(const bf16x8*)(vr + (quad*64 + dt*16 + col) * 8);
        bf16x8 v1 = *(const bf16x8*)(vr + 2048 + (quad*64 + dt*16 + col) * 8);
        oa[dt] = __builtin_amdgcn_mfma_f32_16x16x32_bf16(v0, pa0, oa[dt], 0,0,0);
        oa[dt] = __builtin_amdgcn_mfma_f32_16x16x32_bf16(v1, pa1, oa[dt], 0,0,0);
        ob[dt] = __builtin_amdgcn_mfma_f32_16x16x32_bf16(v0, pb0, ob[dt], 0,0,0);
        ob[dt] = __builtin_amdgcn_mfma_f32_16x16x32_bf16(v1, pb1, ob[dt], 0,0,0);
      }
      __builtin_amdgcn_s_setprio(0);
    }

    __syncthreads();
    cur ^= 1;
  }

  float l0 = (la[0] + la[1]) + (la[2] + la[3]);
  l0 += __shfl_xor(l0, 16);
  l0 += __shfl_xor(l0, 32);
  const float ra = __builtin_amdgcn_rcpf(l0);
  float l1 = (lb[0] + lb[1]) + (lb[2] + lb[3]);
  l1 += __shfl_xor(l1, 16);
  l1 += __shfl_xor(l1, 32);
  const float rb = __builtin_amdgcn_rcpf(l1);

  u16* orow = Oout + (size_t)(b*T_ + q0) * D_ + h*HD_;
#pragma unroll
  for (int dt = 0; dt < 4; ++dt) {
    uint2 w2;
    w2.x = cvtpk(oa[dt][0]*ra, oa[dt][1]*ra);
    w2.y = cvtpk(oa[dt][2]*ra, oa[dt][3]*ra);
    *(uint2*)(orow + dt*16 + quad*4) = w2;
  }
  orow += (size_t)64 * D_;
#pragma unroll
  for (int dt = 0; dt < 4; ++dt) {
    uint2 w2;
    w2.x = cvtpk(ob[dt][0]*rb, ob[dt][1]*rb);
    w2.y = cvtpk(ob[dt][2]*rb, ob[dt][3]*rb);
    *(uint2*)(orow + dt*16 + quad*4) = w2;
  }
}

// ------------------------------- launcher -------------------------------------
extern "C" void kernel_launch(void* const* d_in, const int* in_sizes, int n_in,
                              void* d_out, int out_size, void* d_ws, size_t ws_size,
                              hipStream_t stream) {
  const float* q  = (const float*)d_in[0];
  const float* k  = (const float*)d_in[1];
  const float* v  = (const float*)d_in[2];
  // d_in[3] = mask: causal tril, implemented analytically
  const float* Wq = (const float*)d_in[4];
  const float* bq = (const float*)d_in[5];
  const float* Wk = (const float*)d_in[6];
  const float* bk = (const float*)d_in[7];
  const float* Wv = (const float*)d_in[8];
  const float* bv = (const float*)d_in[9];
  const float* Wo = (const float*)d_in[10];
  const float* bo = (const float*)d_in[11];
  float* out = (float*)d_out;

  char* w = (char*)d_ws;
  const size_t SZ = (size_t)BT_ * D_ * sizeof(u16);   // 16 MiB per tensor
  // workspace: 4x16 MiB + 4x2 MiB = 72 MiB
  u16* Qp = (u16*)(w + 0*SZ);
  u16* Kp = (u16*)(w + 1*SZ);
  u16* Vt = (u16*)(w + 2*SZ);         // written transposed by gemm_qkv seg 2
  u16* AO = (u16*)(w + 3*SZ);         // attention output (bf16)
  u16* Wbq = (u16*)(w + 4*SZ);
  u16* Wbk = (u16*)(w + 4*SZ + 1*(size_t)D_*D_*2);
  u16* Wbv = (u16*)(w + 4*SZ + 2*(size_t)D_*D_*2);
  u16* Wbo = (u16*)(w + 4*SZ + 3*(size_t)D_*D_*2);

  const int n4w = D_ * D_ / 4;
  const int cvw = n4w / 256;
  const int attn_g = (B_*H_) * (T_/128);         // 1024 blocks, longest-first
  dim3 blk(256);

  // weights -> bf16 (1 dispatch); activations converted inside gemm_qkv
  cvt4_f32_bf16<<<4*cvw, blk, 0, stream>>>(Wq, Wk, Wv, Wo,
                                           Wbq, Wbk, Wbv, Wbo, cvw);
  // fused QKV projection, fp32 A converted in-pipeline (V pre-transposed)
  gemm_qkv<<<1536, blk, 0, stream>>>(
      q, k, v, Wbq, Wbk, Wbv, bq, bk, bv, Qp, Kp, Vt, SFC);
  // attention
  attn_fwd<<<attn_g, blk, 0, stream>>>(Qp, Kp, Vt, AO);
  // output projection -> fp32 d_out
  gemm_o<<<1024, blk, 0, stream>>>(AO, Wbo, bo, out);
}

// Round 10
// 323.074 us; speedup vs baseline: 1.0569x; 1.0569x over previous
//
#include <hip/hip_runtime.h>

// Problem constants (B,T,D,H from reference)
#define B_  4
#define T_  2048
#define D_  1024
#define H_  16
#define HD_ 64
#define BT_ (B_*T_)   // 8192
#define K_  D_        // 1024 (GEMM inner dim)

typedef unsigned short u16;
typedef unsigned int   u32;

typedef __attribute__((ext_vector_type(8))) short bf16x8;  // 8 bf16 (4 VGPRs)
typedef __attribute__((ext_vector_type(4))) float f32x4;   // MFMA 16x16 C/D

__device__ __forceinline__ u16 f2bf(float f) {
  u32 u = __builtin_bit_cast(u32, f);
  u += 0x7fffu + ((u >> 16) & 1u);   // round-to-nearest-even
  return (u16)(u >> 16);
}

// packed f32x2 -> bf16x2 (RNE), single VALU op; D[15:0]=lo, D[31:16]=hi
__device__ __forceinline__ u32 cvtpk(float lo, float hi) {
  u32 r;
  __asm__("v_cvt_pk_bf16_f32 %0, %1, %2" : "=v"(r) : "v"(lo), "v"(hi));
  return r;
}

#define GLOAD_LDS16(g, l) __builtin_amdgcn_global_load_lds(                  \
    (const __attribute__((address_space(1))) void*)(g),                      \
    (__attribute__((address_space(3))) void*)(l), 16, 0, 0)

// compiler-only memory barrier: forbids IR reordering of LDS/global ops
#define MEMBAR() __asm__ volatile("" ::: "memory")
#define SCHEDB() __builtin_amdgcn_sched_barrier(0)
#define SBAR()   __builtin_amdgcn_s_barrier()

#define SFC 0.18033688011f   /* 0.125 * log2(e); folded into Q projection */

// ---------------- fp32 -> bf16 converts: q,k,v + 4 weight matrices, 1 launch --
__global__ __launch_bounds__(256) void cvt_all(
    const float* __restrict__ q,  const float* __restrict__ k,
    const float* __restrict__ v,
    const float* __restrict__ w0, const float* __restrict__ w1,
    const float* __restrict__ w2, const float* __restrict__ w3,
    u16* __restrict__ oq, u16* __restrict__ ok, u16* __restrict__ ov,
    u16* __restrict__ x0, u16* __restrict__ x1,
    u16* __restrict__ x2, u16* __restrict__ x3,
    int cvx, int cvw) {
  const int blk = blockIdx.x;
  const float* in;
  u16* out;
  int ib;
  if (blk < 3*cvx) {
    const int seg = (blk >= 2*cvx) ? 2 : (blk >= cvx ? 1 : 0);
    ib  = blk - seg*cvx;
    in  = seg==0 ? q : (seg==1 ? k : v);
    out = seg==0 ? oq : (seg==1 ? ok : ov);
  } else {
    const int wb  = blk - 3*cvx;
    const int seg = wb / cvw;          // 0..3
    ib  = wb - seg*cvw;
    in  = seg==0 ? w0 : (seg==1 ? w1 : (seg==2 ? w2 : w3));
    out = seg==0 ? x0 : (seg==1 ? x1 : (seg==2 ? x2 : x3));
  }
  const int i = ib*256 + threadIdx.x;
  float4 x = ((const float4*)in)[i];
  ((uint2*)out)[i] = make_uint2(cvtpk(x.x, x.y), cvtpk(x.z, x.w));
}

// ---------------- GEMM: 128x128 tile, BK=32, counted-vmcnt pipeline -----------
// (round-4/8 proven: ~77us, MfmaUtil 27, 0 bank conflicts — FROZEN)
// QKV-fused: seg = blockIdx.x>>9 selects {A,W,bias,Out} (grid 1536 = 3x512).
// Pipeline (T4): STAGE(t+1) at top of iter t; `s_waitcnt vmcnt(4)` (never 0
// in-loop) guarantees tile t landed; raw s_barrier publishes.
// seg==2 (V projection) writes its output TRANSPOSED to Vt[b,h,hd,t].
__global__ __launch_bounds__(256, 4) void gemm_qkv(
    const u16* __restrict__ A0, const u16* __restrict__ A1,
    const u16* __restrict__ A2,
    const u16* __restrict__ W0, const u16* __restrict__ W1,
    const u16* __restrict__ W2,
    const float* __restrict__ b0, const float* __restrict__ b1,
    const float* __restrict__ b2,
    u16* __restrict__ O0, u16* __restrict__ O1, u16* __restrict__ O2,
    float osc0)
{
  __shared__ u16 As[2][128 * 32];   // [buf][row][slot][8]
  __shared__ u16 Bs[2][128 * 32];

  const int tid  = threadIdx.x;
  const int wave = tid >> 6;
  const int lane = tid & 63;
  const int col  = lane & 15;
  const int quad = lane >> 4;
  const int wy   = wave >> 1;          // m-half (64)
  const int wx   = wave & 1;           // n-half (64)

  const int seg   = blockIdx.x >> 9;   // 0=Q 1=K 2=V
  const int inner = blockIdx.x & 511;
  const u16*  A    = seg==0 ? A0 : (seg==1 ? A1 : A2);
  const u16*  W    = seg==0 ? W0 : (seg==1 ? W1 : W2);
  const float* bias = seg==0 ? b0 : (seg==1 ? b1 : b2);
  u16*        Out  = seg==0 ? O0 : (seg==1 ? O1 : O2);
  const float oscale = (seg == 0) ? osc0 : 1.0f;

  // XCD-clustered swizzle within the 512-block segment
  const int xcd = inner & 7;
  const int jj  = inner >> 3;          // 0..63
  const int m0 = (xcd*8 + (jj & 7)) * 128;
  const int n0 = (jj >> 3) * 128;

  // staging: 4 threads/row; physical slot tid&3 holds k-chunk (tid&3)^((row>>1)&3)
  const int srow = tid >> 2;                           // 0..63
  const int kseg = ((tid & 3) ^ ((srow >> 1) & 3)) * 8;
  const u16* agp = A + (size_t)(m0 + srow) * K_ + kseg;
  const u16* bgp = W + (size_t)(n0 + srow) * K_ + kseg;

  f32x4 acc[4][4];
  const f32x4 z = {0.f, 0.f, 0.f, 0.f};
#pragma unroll
  for (int i = 0; i < 4; ++i)
#pragma unroll
    for (int j = 0; j < 4; ++j) acc[i][j] = z;

  // frag LDS offsets (u16): row*32 + (quad ^ ((row>>1)&3))*8
  u32 aro[4], bro[4];
#pragma unroll
  for (int i = 0; i < 4; ++i) {
    const int ar = wy*64 + i*16 + col;
    const int br = wx*64 + i*16 + col;
    aro[i] = (u32)(ar*32 + ((quad ^ ((ar >> 1) & 3)) * 8));
    bro[i] = (u32)(br*32 + ((quad ^ ((br >> 1) & 3)) * 8));
  }

  auto STAGE = [&](int buf, int k0) {
    GLOAD_LDS16(agp + k0,                 &As[buf][tid*8]);
    GLOAD_LDS16(agp + (size_t)64*K_ + k0, &As[buf][2048 + tid*8]);
    GLOAD_LDS16(bgp + k0,                 &Bs[buf][tid*8]);
    GLOAD_LDS16(bgp + (size_t)64*K_ + k0, &Bs[buf][2048 + tid*8]);
  };

  STAGE(0, 0);
  MEMBAR();

  int cur = 0;
  for (int k0 = 0; k0 < K_; k0 += 32) {
    if (k0 + 32 < K_) {
      STAGE(cur ^ 1, k0 + 32);    // prefetch next K-slice (4 loads/wave)
      MEMBAR();
      __asm__ volatile("s_waitcnt vmcnt(4)" ::: "memory");  // tile t landed
    } else {
      __asm__ volatile("s_waitcnt vmcnt(0)" ::: "memory");  // last tile
    }
    SCHEDB();
    SBAR();            // publish: all waves' tile-t loads are in LDS
    MEMBAR();
    SCHEDB();

    bf16x8 af[4], bfr[4];
#pragma unroll
    for (int i = 0; i < 4; ++i) af[i]  = *(const bf16x8*)(&As[cur][aro[i]]);
#pragma unroll
    for (int i = 0; i < 4; ++i) bfr[i] = *(const bf16x8*)(&Bs[cur][bro[i]]);
    __asm__ volatile("s_waitcnt lgkmcnt(0)" ::: "memory");
    SCHEDB();
#pragma unroll
    for (int mt = 0; mt < 4; ++mt)
#pragma unroll
      for (int nt = 0; nt < 4; ++nt)
        acc[mt][nt] = __builtin_amdgcn_mfma_f32_16x16x32_bf16(
            bfr[nt], af[mt], acc[mt][nt], 0, 0, 0);   // swapped: regs = n-dim

    SCHEDB();
    SBAR();            // readers done -> buffer safe to restage next iter
    MEMBAR();
    SCHEDB();
    cur ^= 1;
  }

  // epilogue: lane holds 4 consecutive n per (mt,nt)
#pragma unroll
  for (int nt = 0; nt < 4; ++nt) {
    const int nb = n0 + wx*64 + nt*16 + quad*4;
    const float4 bv = *(const float4*)&bias[nb];
#pragma unroll
    for (int mt = 0; mt < 4; ++mt) {
      const int m = m0 + wy*64 + mt*16 + col;
      const float v0 = (acc[mt][nt][0] + bv.x) * oscale;
      const float v1 = (acc[mt][nt][1] + bv.y) * oscale;
      const float v2 = (acc[mt][nt][2] + bv.z) * oscale;
      const float v3 = (acc[mt][nt][3] + bv.w) * oscale;
      if (seg != 2) {
        uint2 w2 = make_uint2(cvtpk(v0, v1), cvtpk(v2, v3));
        *(uint2*)&Out[(size_t)m * D_ + nb] = w2;
      } else {
        // V: write transposed Vt[(b*16+h)*64+hd][t]
        const int bb = m >> 11, tt = m & 2047;
        const int h = nb >> 6, hd = nb & 63;
        u16* vp = Out + ((size_t)((bb*16 + h)*64 + hd)) * 2048 + tt;
        vp[0]    = f2bf(v0);
        vp[2048] = f2bf(v1);
        vp[4096] = f2bf(v2);
        vp[6144] = f2bf(v3);
      }
    }
  }
}

// ---------------- O-projection GEMM: 64x128 tile, grid 1024 -------------------
// (round-4/8 proven structure: 4 blocks/CU, counted vmcnt(3), bias epilogue)
__global__ __launch_bounds__(256, 4) void gemm_o(
    const u16* __restrict__ A, const u16* __restrict__ W,
    const float* __restrict__ bias, float* __restrict__ Out)
{
  __shared__ u16 As[2][64 * 32];
  __shared__ u16 Bs[2][128 * 32];

  const int tid  = threadIdx.x;
  const int wave = tid >> 6;
  const int lane = tid & 63;
  const int col  = lane & 15;
  const int quad = lane >> 4;
  const int wy   = wave >> 1;          // m-half (32)
  const int wx   = wave & 1;           // n-half (64)

  const int xcd = blockIdx.x & 7;
  const int jj  = blockIdx.x >> 3;     // 0..127
  const int m0 = (xcd*16 + (jj & 15)) * 64;
  const int n0 = (jj >> 4) * 128;

  const int srow = tid >> 2;                           // 0..63
  const int kseg = ((tid & 3) ^ ((srow >> 1) & 3)) * 8;
  const u16* agp = A + (size_t)(m0 + srow) * K_ + kseg;
  const u16* bgp = W + (size_t)(n0 + srow) * K_ + kseg;

  f32x4 acc[2][4];
  const f32x4 z = {0.f, 0.f, 0.f, 0.f};
#pragma unroll
  for (int i = 0; i < 2; ++i)
#pragma unroll
    for (int j = 0; j < 4; ++j) acc[i][j] = z;

  u32 aro[2], bro[4];
#pragma unroll
  for (int i = 0; i < 2; ++i) {
    const int ar = wy*32 + i*16 + col;
    aro[i] = (u32)(ar*32 + ((quad ^ ((ar >> 1) & 3)) * 8));
  }
#pragma unroll
  for (int i = 0; i < 4; ++i) {
    const int br = wx*64 + i*16 + col;
    bro[i] = (u32)(br*32 + ((quad ^ ((br >> 1) & 3)) * 8));
  }

  auto STAGE = [&](int buf, int k0) {
    GLOAD_LDS16(agp + k0,                 &As[buf][tid*8]);
    GLOAD_LDS16(bgp + k0,                 &Bs[buf][tid*8]);
    GLOAD_LDS16(bgp + (size_t)64*K_ + k0, &Bs[buf][2048 + tid*8]);
  };

  STAGE(0, 0);
  MEMBAR();

  int cur = 0;
  for (int k0 = 0; k0 < K_; k0 += 32) {
    if (k0 + 32 < K_) {
      STAGE(cur ^ 1, k0 + 32);    // prefetch next K-slice (3 loads/wave)
      MEMBAR();
      __asm__ volatile("s_waitcnt vmcnt(3)" ::: "memory");
    } else {
      __asm__ volatile("s_waitcnt vmcnt(0)" ::: "memory");
    }
    SCHEDB();
    SBAR();
    MEMBAR();
    SCHEDB();

    bf16x8 af[2], bfr[4];
#pragma unroll
    for (int i = 0; i < 2; ++i) af[i]  = *(const bf16x8*)(&As[cur][aro[i]]);
#pragma unroll
    for (int i = 0; i < 4; ++i) bfr[i] = *(const bf16x8*)(&Bs[cur][bro[i]]);
    __asm__ volatile("s_waitcnt lgkmcnt(0)" ::: "memory");
    SCHEDB();
#pragma unroll
    for (int mt = 0; mt < 2; ++mt)
#pragma unroll
      for (int nt = 0; nt < 4; ++nt)
        acc[mt][nt] = __builtin_amdgcn_mfma_f32_16x16x32_bf16(
            bfr[nt], af[mt], acc[mt][nt], 0, 0, 0);

    SCHEDB();
    SBAR();
    MEMBAR();
    SCHEDB();
    cur ^= 1;
  }

#pragma unroll
  for (int nt = 0; nt < 4; ++nt) {
    const int nb = n0 + wx*64 + nt*16 + quad*4;
    const float4 bv = *(const float4*)&bias[nb];
#pragma unroll
    for (int mt = 0; mt < 2; ++mt) {
      const int m = m0 + wy*32 + mt*16 + col;
      float4 f4 = {acc[mt][nt][0] + bv.x, acc[mt][nt][1] + bv.y,
                   acc[mt][nt][2] + bv.z, acc[mt][nt][3] + bv.w};
      *(float4*)&Out[(size_t)m * D_ + nb] = f4;
    }
  }
}

// ---------------- Flash attention: dbuf-staged K/V, 128-row q-blocks ----------
// (cvtpk version — verified; FROZEN)
__global__ __launch_bounds__(256) void attn_fwd(
    const u16* __restrict__ Qp, const u16* __restrict__ Kp,
    const u16* __restrict__ Vt, u16* __restrict__ Oout)
{
  __shared__ u16 Ks[2 * 4096];  // [buf][slot=hd/8][row=j][8]
  __shared__ u16 Vs[2 * 4096];  // [buf][slot=t/8][row=hd][8]
  __shared__ __align__(16) u16 plds[4 * 32 * 72];   // per-wave P, stride 72

  const int tid  = threadIdx.x;
  const int wave = tid >> 6;
  const int lane = tid & 63;
  const int col  = lane & 15;
  const int quad = lane >> 4;
  const int blk  = blockIdx.x;
  const int bh   = blk & 63;
  const int qt   = 15 - (blk >> 6);   // longest blocks first
  const int b = bh >> 4, h = bh & 15;
  const int rb0 = qt*128 + wave*16;   // group0 rows
  const int q0 = rb0 + col;
  const int q1 = q0 + 64;

  u16* const pl = plds + wave * 32 * 72;   // rows 0..15 grp0, 16..31 grp1

  bf16x8 qa0, qa1, qb0, qb1;
  {
    const u16* qr = Qp + (size_t)(b*T_ + q0) * D_ + h*HD_ + quad*8;
    qa0 = *(const bf16x8*)(qr);
    qa1 = *(const bf16x8*)(qr + 32);
    qr += (size_t)64 * D_;
    qb0 = *(const bf16x8*)(qr);
    qb1 = *(const bf16x8*)(qr + 32);
  }

  const u16* kbase = Kp + (size_t)(b*T_) * D_ + h*HD_;
  const u16* vbase = Vt + (size_t)(bh*HD_) * T_;

  const int srow  = tid & 63;
  const int sslot = tid >> 6;
  const u16* kg0 = kbase + (size_t)srow * D_ + sslot*8;
  const u16* kg1 = kbase + (size_t)srow * D_ + (4+sslot)*8;
  const u16* vg0 = vbase + (size_t)srow * T_ + sslot*8;
  const u16* vg1 = vbase + (size_t)srow * T_ + (4+sslot)*8;

  const f32x4 z = {0.f, 0.f, 0.f, 0.f};
  f32x4 oa[4], ob[4];
#pragma unroll
  for (int dt = 0; dt < 4; ++dt) { oa[dt] = z; ob[dt] = z; }
  f32x4 la = z, lb = z;

  const int jend0  = qt * 128;
  const int jend1  = qt * 128 + 64;
  const int ntiles = (jend1 >> 6) + 1;

  GLOAD_LDS16(kg0, Ks + tid*8);
  GLOAD_LDS16(kg1, Ks + 2048 + tid*8);
  GLOAD_LDS16(vg0, Vs + tid*8);
  GLOAD_LDS16(vg1, Vs + 2048 + tid*8);
  __syncthreads();

  int cur = 0;
  for (int t = 0; t < ntiles; ++t) {
    const int j0 = t << 6;

    if (t + 1 < ntiles) {
      const int jn = j0 + 64;
      const size_t kj = (size_t)jn * D_;
      u16* kb = Ks + (cur ^ 1) * 4096;
      u16* vb = Vs + (cur ^ 1) * 4096;
      GLOAD_LDS16(kg0 + kj, kb + tid*8);
      GLOAD_LDS16(kg1 + kj, kb + 2048 + tid*8);
      GLOAD_LDS16(vg0 + jn, vb + tid*8);
      GLOAD_LDS16(vg1 + jn, vb + 2048 + tid*8);
    }
    MEMBAR();

    const u16* kr = Ks + cur * 4096;
    const u16* vr = Vs + cur * 4096;

    f32x4 sa[4], sb[4];
    __builtin_amdgcn_s_setprio(1);
#pragma unroll
    for (int jt = 0; jt < 4; ++jt) {
      bf16x8 kf0 = *(const bf16x8*)(kr + (quad*64 + jt*16 + col) * 8);
      bf16x8 kf1 = *(const bf16x8*)(kr + 2048 + (quad*64 + jt*16 + col) * 8);
      sa[jt] = __builtin_amdgcn_mfma_f32_16x16x32_bf16(kf0, qa0, z, 0,0,0);
      sa[jt] = __builtin_amdgcn_mfma_f32_16x16x32_bf16(kf1, qa1, sa[jt], 0,0,0);
      sb[jt] = __builtin_amdgcn_mfma_f32_16x16x32_bf16(kf0, qb0, z, 0,0,0);
      sb[jt] = __builtin_amdgcn_mfma_f32_16x16x32_bf16(kf1, qb1, sb[jt], 0,0,0);
    }
    __builtin_amdgcn_s_setprio(0);

    if (j0 >= jend0) {
      const int dq = q0 - j0;
#pragma unroll
      for (int jt = 0; jt < 4; ++jt)
#pragma unroll
        for (int r = 0; r < 4; ++r) {
          const int jo = jt*16 + quad*4 + r;
          sa[jt][r] = (jo > dq) ? 0.f : __builtin_amdgcn_exp2f(sa[jt][r]);
        }
    } else {
#pragma unroll
      for (int jt = 0; jt < 4; ++jt)
#pragma unroll
        for (int r = 0; r < 4; ++r)
          sa[jt][r] = __builtin_amdgcn_exp2f(sa[jt][r]);
    }
    if (j0 >= jend1) {
      const int dq = q1 - j0;
#pragma unroll
      for (int jt = 0; jt < 4; ++jt)
#pragma unroll
        for (int r = 0; r < 4; ++r) {
          const int jo = jt*16 + quad*4 + r;
          sb[jt][r] = (jo > dq) ? 0.f : __builtin_amdgcn_exp2f(sb[jt][r]);
        }
    } else {
#pragma unroll
      for (int jt = 0; jt < 4; ++jt)
#pragma unroll
        for (int r = 0; r < 4; ++r)
          sb[jt][r] = __builtin_amdgcn_exp2f(sb[jt][r]);
    }
#pragma unroll
    for (int jt = 0; jt < 4; ++jt) { la += sa[jt]; lb += sb[jt]; }

    {
      u16* prow = pl + col * 72;
#pragma unroll
      for (int jt = 0; jt < 4; ++jt) {
        uint2 w2;
        w2.x = cvtpk(sa[jt][0], sa[jt][1]);
        w2.y = cvtpk(sa[jt][2], sa[jt][3]);
        *(uint2*)(prow + jt*16 + quad*4) = w2;
      }
      prow = pl + (16 + col) * 72;
#pragma unroll
      for (int jt = 0; jt < 4; ++jt) {
        uint2 w2;
        w2.x = cvtpk(sb[jt][0], sb[jt][1]);
        w2.y = cvtpk(sb[jt][2], sb[jt][3]);
        *(uint2*)(prow + jt*16 + quad*4) = w2;
      }
    }
    MEMBAR();

    {
      bf16x8 pa0 = *(const bf16x8*)(pl + col*72 + quad*8);
      bf16x8 pa1 = *(const bf16x8*)(pl + col*72 + 32 + quad*8);
      bf16x8 pb0 = *(const bf16x8*)(pl + (16+col)*72 + quad*8);
      bf16x8 pb1 = *(const bf16x8*)(pl + (16+col)*72 + 32 + quad*8);
      __builtin_amdgcn_s_setprio(1);
#pragma unroll
      for (int dt = 0; dt < 4; ++dt) {
        bf16x8 v0 = *(const bf16x8*)(vr + (quad*64 + dt*16 + col) * 8);
        bf16x8 v1 = *(const bf16x8*)(vr + 2048 + (quad*64 + dt*16 + col) * 8);
        oa[dt] = __builtin_amdgcn_mfma_f32_16x16x32_bf16(v0, pa0, oa[dt], 0,0,0);
        oa[dt] = __builtin_amdgcn_mfma_f32_16x16x32_bf16(v1, pa1, oa[dt], 0,0,0);
        ob[dt] = __builtin_amdgcn_mfma_f32_16x16x32_bf16(v0, pb0, ob[dt], 0,0,0);
        ob[dt] = __builtin_amdgcn_mfma_f32_16x16x32_bf16(v1, pb1, ob[dt], 0,0,0);
      }
      __builtin_amdgcn_s_setprio(0);
    }

    __syncthreads();
    cur ^= 1;
  }

  float l0 = (la[0] + la[1]) + (la[2] + la[3]);
  l0 += __shfl_xor(l0, 16);
  l0 += __shfl_xor(l0, 32);
  const float ra = __builtin_amdgcn_rcpf(l0);
  float l1 = (lb[0] + lb[1]) + (lb[2] + lb[3]);
  l1 += __shfl_xor(l1, 16);
  l1 += __shfl_xor(l1, 32);
  const float rb = __builtin_amdgcn_rcpf(l1);

  u16* orow = Oout + (size_t)(b*T_ + q0) * D_ + h*HD_;
#pragma unroll
  for (int dt = 0; dt < 4; ++dt) {
    uint2 w2;
    w2.x = cvtpk(oa[dt][0]*ra, oa[dt][1]*ra);
    w2.y = cvtpk(oa[dt][2]*ra, oa[dt][3]*ra);
    *(uint2*)(orow + dt*16 + quad*4) = w2;
  }
  orow += (size_t)64 * D_;
#pragma unroll
  for (int dt = 0; dt < 4; ++dt) {
    uint2 w2;
    w2.x = cvtpk(ob[dt][0]*rb, ob[dt][1]*rb);
    w2.y = cvtpk(ob[dt][2]*rb, ob[dt][3]*rb);
    *(uint2*)(orow + dt*16 + quad*4) = w2;
  }
}

// ------------------------------- launcher -------------------------------------
extern "C" void kernel_launch(void* const* d_in, const int* in_sizes, int n_in,
                              void* d_out, int out_size, void* d_ws, size_t ws_size,
                              hipStream_t stream) {
  const float* q  = (const float*)d_in[0];
  const float* k  = (const float*)d_in[1];
  const float* v  = (const float*)d_in[2];
  // d_in[3] = mask: causal tril, implemented analytically
  const float* Wq = (const float*)d_in[4];
  const float* bq = (const float*)d_in[5];
  const float* Wk = (const float*)d_in[6];
  const float* bk = (const float*)d_in[7];
  const float* Wv = (const float*)d_in[8];
  const float* bv = (const float*)d_in[9];
  const float* Wo = (const float*)d_in[10];
  const float* bo = (const float*)d_in[11];
  float* out = (float*)d_out;

  char* w = (char*)d_ws;
  const size_t SZ = (size_t)BT_ * D_ * sizeof(u16);   // 16 MiB per tensor
  // workspace: 6x16 MiB + 4x2 MiB = 104 MiB
  u16* Xq = (u16*)(w + 0*SZ);         // q-act bf16; later attention output
  u16* Xk = (u16*)(w + 1*SZ);
  u16* Xv = (u16*)(w + 2*SZ);
  u16* Qp = (u16*)(w + 3*SZ);
  u16* Kp = (u16*)(w + 4*SZ);
  u16* Vt = (u16*)(w + 5*SZ);         // written transposed by gemm_qkv seg 2
  u16* Wbq = (u16*)(w + 6*SZ);
  u16* Wbk = (u16*)(w + 6*SZ + 1*(size_t)D_*D_*2);
  u16* Wbv = (u16*)(w + 6*SZ + 2*(size_t)D_*D_*2);
  u16* Wbo = (u16*)(w + 6*SZ + 3*(size_t)D_*D_*2);
  u16* AO = Xq;

  const int n4x = BT_ * D_ / 4;
  const int n4w = D_ * D_ / 4;
  const int cvx = n4x / 256, cvw = n4w / 256;
  const int attn_g = (B_*H_) * (T_/128);         // 1024 blocks, longest-first
  dim3 blk(256);

  // all 7 fp32->bf16 converts in ONE dispatch (3 activations + 4 weights)
  cvt_all<<<3*cvx + 4*cvw, blk, 0, stream>>>(
      q, k, v, Wq, Wk, Wv, Wo,
      Xq, Xk, Xv, Wbq, Wbk, Wbv, Wbo, cvx, cvw);
  // fused QKV projection (V written pre-transposed)
  gemm_qkv<<<1536, blk, 0, stream>>>(
      Xq, Xk, Xv, Wbq, Wbk, Wbv, bq, bk, bv, Qp, Kp, Vt, SFC);
  // attention
  attn_fwd<<<attn_g, blk, 0, stream>>>(Qp, Kp, Vt, AO);
  // output projection -> fp32 d_out
  gemm_o<<<1024, blk, 0, stream>>>(AO, Wbo, bo, out);
}